// Round 15
// baseline (300.908 us; speedup 1.0000x reference)
//
#include <hip/hip_runtime.h>
#include <stdint.h>

#define DIM   2048
#define LSEQ  2048
#define BATCH 2
#define NH    32
#define NKV   8
#define HD    64
#define M_ROWS (BATCH*LSEQ)       // 4096
#define NQKV  (DIM + 2*NKV*HD)    // 3072
#define KOFF  DIM                 // 2048
#define VOFF  (DIM + NKV*HD)      // 2560

typedef __attribute__((ext_vector_type(8))) __bf16 bf16x8;
typedef __attribute__((ext_vector_type(8))) unsigned short u16x8;
typedef __attribute__((ext_vector_type(4))) float f32x4;

// hardware RNE f32->bf16 (harness-verified rounds 2-14)
__device__ __forceinline__ unsigned short f2bf(float f) {
  union { __bf16 h; unsigned short u; } v;
  v.h = (__bf16)f;
  return v.u;
}
__device__ __forceinline__ float bf2f(unsigned short h) {
  union { unsigned u; float f; } v; v.u = ((unsigned)h) << 16;
  return v.f;
}

__device__ __forceinline__ void gload_lds16(const void* g, void* l) {
  __builtin_amdgcn_global_load_lds(
      (__attribute__((address_space(1))) unsigned int*)g,
      (__attribute__((address_space(3))) unsigned int*)l, 16, 0, 0);
}

// ---------------- fp32 -> bf16 convert (vectorized) ----------------
__global__ void k_cvt_x(const float* __restrict__ in, unsigned short* __restrict__ out, int n4) {
  int i = blockIdx.x * blockDim.x + threadIdx.x;
  if (i >= n4) return;
  float4 v = ((const float4*)in)[i];
  ushort4 o;
  o.x = f2bf(v.x); o.y = f2bf(v.y); o.z = f2bf(v.z); o.w = f2bf(v.w);
  ((ushort4*)out)[i] = o;
}

// ---------------- fused weight transposes: 4 launches -> 1 (z-sectioned) ----------------
__global__ void k_transpose_all(const float* __restrict__ wq, const float* __restrict__ wk,
                                const float* __restrict__ wv, const float* __restrict__ wo,
                                unsigned short* __restrict__ wqkvT,
                                unsigned short* __restrict__ woT, float C2) {
  __shared__ float tile[32][33];
  int sec = blockIdx.z;
  const float* in; unsigned short* out; int N; float scale = 1.0f;
  if (sec == 0)      { in = wq; out = wqkvT;                     N = DIM; scale = C2; }
  else if (sec == 1) { in = wk; out = wqkvT + (long)2048 * 2048; N = 512; }
  else if (sec == 2) { in = wv; out = wqkvT + (long)2560 * 2048; N = 512; }
  else               { in = wo; out = woT;                       N = DIM; }
  int n0 = blockIdx.x * 32;
  if (n0 >= N) return;
  int k0 = blockIdx.y * 32;
  int tx = threadIdx.x, ty = threadIdx.y;
  #pragma unroll
  for (int i = ty; i < 32; i += 8)
    tile[i][tx] = in[(long)(k0 + i) * N + n0 + tx];
  __syncthreads();
  #pragma unroll
  for (int i = ty; i < 32; i += 8)
    out[(long)(n0 + i) * DIM + k0 + tx] = f2bf(scale * tile[tx][i]);
}

// ---------------- transpose V section of qkv -> vT, k-PERMUTED columns ----------------
// Column position e holds original k = tx with e = 8*((tx>>2)&3) + 4*(tx>>4) + (tx&3),
// matching flash's in-register-P A-fragment k-order (round 6/7, verified).
__global__ void k_transpose_v(const unsigned short* __restrict__ qkv,
                              unsigned short* __restrict__ vT) {
  __shared__ unsigned short tile[32][33];
  int c0 = blockIdx.x * 32;   // within 512 (= g*64+d)
  int l0 = blockIdx.y * 32;
  int b  = blockIdx.z;
  int tx = threadIdx.x, ty = threadIdx.y;
  #pragma unroll
  for (int i = ty; i < 32; i += 8)
    tile[i][tx] = qkv[((long)b * LSEQ + l0 + i) * NQKV + VOFF + c0 + tx];
  __syncthreads();
  int e = 8 * ((tx >> 2) & 3) + 4 * (tx >> 4) + (tx & 3);
  #pragma unroll
  for (int i = ty; i < 32; i += 8)
    vT[((long)b * 512 + c0 + i) * LSEQ + l0 + e] = tile[tx][i];
}

// ---------------- RoPE tables ----------------
__global__ void k_rope_table(float* __restrict__ cosT, float* __restrict__ sinT) {
  int i = blockIdx.x * 256 + threadIdx.x;  // < LSEQ*32
  int t = i >> 5, j = i & 31;
  float inv = powf(10000.0f, -(float)j / 32.0f);
  float fr = (float)t * inv;
  cosT[i] = cosf(fr);
  sinT[i] = sinf(fr);
}

// ---------------- GEMM v8 (QKV): 128^2 tile, BK=64, 512 threads / 8 waves (r13, verified) ----------------
template<bool BF16OUT, bool ROPE>
__global__ __launch_bounds__(512, 4) void k_gemm_bt(
    const unsigned short* __restrict__ A, const unsigned short* __restrict__ Bt,
    void* __restrict__ Cv, int M, int N, int K,
    const float* __restrict__ cosT, const float* __restrict__ sinT) {
  __shared__ __align__(16) char AsB[16384];   // [128 rows][128B], swizzled
  __shared__ __align__(16) char BsB[16384];
  int t = threadIdx.x;
  int lane = t & 63, wave = t >> 6;        // 0..7
  int fr = lane & 15, fg = lane >> 4;
  int wm = wave >> 1, wn = wave & 1;       // 4M x 2N quadrants: 32 rows x 64 cols
  long rowA = (long)blockIdx.x * 128;
  long rowB = (long)blockIdx.y * 128;
  long K2 = (long)K * 2;

  int scol = ((t & 7) * 16) ^ (((t >> 3) & 7) << 4);
  const char* ApB = (const char*)A  + (rowA + (t >> 3)) * K2 + scol;
  const char* BpB = (const char*)Bt + (rowB + (t >> 3)) * K2 + scol;

  f32x4 acc[2][4] = {};
  int sw8 = (fr & 7) << 4;

  for (int kt = 0; kt < K; kt += 64) {
    #pragma unroll
    for (int p = 0; p < 2; p++) {
      gload_lds16(ApB + (long)(p * 64) * K2 + kt * 2, AsB + p * 8192 + t * 16);
      gload_lds16(BpB + (long)(p * 64) * K2 + kt * 2, BsB + p * 8192 + t * 16);
    }
    __syncthreads();
    #pragma unroll
    for (int ks = 0; ks < 2; ks++) {
      bf16x8 af[2], bfv[4];
      #pragma unroll
      for (int i = 0; i < 2; i++)
        af[i] = *(const bf16x8*)(AsB + (wm * 32 + i * 16 + fr) * 128 + ((ks * 64 + fg * 16) ^ sw8));
      #pragma unroll
      for (int j = 0; j < 4; j++)
        bfv[j] = *(const bf16x8*)(BsB + (wn * 64 + j * 16 + fr) * 128 + ((ks * 64 + fg * 16) ^ sw8));
      #pragma unroll
      for (int i = 0; i < 2; i++) {
        #pragma unroll
        for (int j = 0; j < 4; j++)
          acc[i][j] = __builtin_amdgcn_mfma_f32_16x16x32_bf16(af[i], bfv[j], acc[i][j], 0, 0, 0);
      }
    }
    __syncthreads();
  }

  long colbase = rowB + wn * 64;
  bool rope_sec = ROPE && (colbase < VOFF);   // Q or K head (col < 2560); wave-uniform
  #pragma unroll
  for (int i = 0; i < 2; i++) {
    #pragma unroll
    for (int r = 0; r < 4; r++) {
      long row = rowA + wm * 32 + i * 16 + fg * 4 + r;
      if (ROPE && rope_sec) {
        int tpos = (int)(row & (LSEQ - 1));
        #pragma unroll
        for (int j = 0; j < 2; j++) {   // pair (d = j*16+fr, d+32 = (j+2)*16+fr)
          int jj = j * 16 + fr;
          float c = cosT[tpos * 32 + jj];
          float s = sinT[tpos * 32 + jj];
          float lo = acc[i][j][r], hi = acc[i][j + 2][r];
          ((unsigned short*)Cv)[row * N + colbase + j * 16 + fr]       = f2bf(lo * c - hi * s);
          ((unsigned short*)Cv)[row * N + colbase + (j + 2) * 16 + fr] = f2bf(hi * c + lo * s);
        }
      } else {
        #pragma unroll
        for (int j = 0; j < 4; j++) {
          long col = colbase + j * 16 + fr;
          if (BF16OUT) ((unsigned short*)Cv)[row * N + col] = f2bf(acc[i][j][r]);
          else         ((float*)Cv)[row * N + col] = acc[i][j][r];
        }
      }
    }
  }
}

// ---------------- GEMM v9 (WO): 128^2 dbuf single-barrier pipeline, 512 threads (r13, verified) ----------------
__global__ __launch_bounds__(512, 4) void k_gemm_db(
    const unsigned short* __restrict__ A, const unsigned short* __restrict__ Bt,
    float* __restrict__ Cv, int M, int N, int K) {
  __shared__ __align__(16) char AsB[2][16384];   // [buf][128 rows][128B], swizzled
  __shared__ __align__(16) char BsB[2][16384];
  int t = threadIdx.x;
  int lane = t & 63, wave = t >> 6;
  int fr = lane & 15, fg = lane >> 4;
  int wm = wave >> 1, wn = wave & 1;       // 4M x 2N quadrants: 32 rows x 64 cols
  long rowA = (long)blockIdx.x * 128;
  long rowB = (long)blockIdx.y * 128;
  long K2 = (long)K * 2;

  int scol = ((t & 7) * 16) ^ (((t >> 3) & 7) << 4);
  const char* ApB = (const char*)A  + (rowA + (t >> 3)) * K2 + scol;
  const char* BpB = (const char*)Bt + (rowB + (t >> 3)) * K2 + scol;

  auto stage = [&](int kt, int bi) {   // kt in 64-elem tiles; 4 loads/thread
    #pragma unroll
    for (int p = 0; p < 2; p++) {
      gload_lds16(ApB + (long)(p * 64) * K2 + (long)kt * 128, AsB[bi] + p * 8192 + t * 16);
      gload_lds16(BpB + (long)(p * 64) * K2 + (long)kt * 128, BsB[bi] + p * 8192 + t * 16);
    }
  };

  f32x4 acc[2][4] = {};
  int sw8 = (fr & 7) << 4;
  int NT = K >> 6;

  stage(0, 0);
  for (int kt = 0; kt < NT; kt++) {
    int cur = kt & 1;
    asm volatile("s_waitcnt vmcnt(0)" ::: "memory");
    __builtin_amdgcn_s_barrier();
    __builtin_amdgcn_sched_barrier(0);
    const char* Ac = AsB[cur];
    const char* Bc = BsB[cur];
    #pragma unroll
    for (int ks = 0; ks < 2; ks++) {
      bf16x8 af[2], bfv[4];
      #pragma unroll
      for (int i = 0; i < 2; i++)
        af[i] = *(const bf16x8*)(Ac + (wm * 32 + i * 16 + fr) * 128 + ((ks * 64 + fg * 16) ^ sw8));
      #pragma unroll
      for (int j = 0; j < 4; j++)
        bfv[j] = *(const bf16x8*)(Bc + (wn * 64 + j * 16 + fr) * 128 + ((ks * 64 + fg * 16) ^ sw8));
      if (ks == 0 && kt + 1 < NT) stage(kt + 1, cur ^ 1);   // issue under reads+MFMA
      #pragma unroll
      for (int i = 0; i < 2; i++) {
        #pragma unroll
        for (int j = 0; j < 4; j++)
          acc[i][j] = __builtin_amdgcn_mfma_f32_16x16x32_bf16(af[i], bfv[j], acc[i][j], 0, 0, 0);
      }
    }
  }

  #pragma unroll
  for (int i = 0; i < 2; i++) {
    #pragma unroll
    for (int j = 0; j < 4; j++) {
      #pragma unroll
      for (int r = 0; r < 4; r++) {
        long row = rowA + wm * 32 + i * 16 + fg * 4 + r;
        long col = rowB + wn * 64 + j * 16 + fr;
        Cv[row * N + col] = acc[i][j][r];
      }
    }
  }
}

// ---------------- flash attention v18: 8-wave blocks, 256 q-rows, shared K/V staging ----------------
// Round-15: v17 is concurrency-starved (~2 waves/SIMD effective; 2.2K cy/iter-slot vs
// ~600 cy issue work) with per-128-q-rows staging overhead. Restructure: 512-thread
// blocks own 256 q-rows (8 waves x 32); ONE staged K/V tile shared by all 8 waves.
// Per-wave code is byte-identical to v17 (same frag maps, mask, pack, PV, ones-MFMA
// denominator, epilogue). Changes: staging per thread halves (4 gloads/iter); grid 512
// -> 2 blocks/CU x 8 waves = 16 waves/CU (2x latency hiding; LDS 48KB unchanged);
// waves whose q-rows lie entirely below the current k-tile (kbase >= qbaseA+32) skip
// compute via the r2-proven active guard (still stage + barrier). Per-wave causal mask
// fires on kbase+127 > qbaseA (covers the wave-local diagonal; no-op when clear).
// Staging maps rederived for 512 threads, same inverse-swizzle invariants
// (dest = t*16 keeps wave-uniform base; row&7 == (t>>3)&7 / (t>>4)&7 hold).
__global__ __launch_bounds__(512, 4) void k_flash_attn15(
    const unsigned short* __restrict__ qkv, const unsigned short* __restrict__ vT,
    unsigned short* __restrict__ attn) {
  int g0 = (int)blockIdx.x;
  int hb = g0 & 63;
  int h = hb & 31, b = hb >> 5;
  int qblk = 7 - (g0 >> 6);           // heavy blocks first (backfill smooths the tail)
  int g = h >> 2;
  int t = threadIdx.x, lane = t & 63, wave = t >> 6;   // wave 0..7
  int fr = lane & 15, fg = lane >> 4;

  __shared__ __align__(16) char KT[16384];              // 16KB: K tile [128 rows][128B], swz
  __shared__ __align__(16) char VT2[2][16384];          // 32KB: V tile [64 rows][256B], swz, dbuf
  long rowbase = (long)b * LSEQ;

  int qbaseA = qblk * 256 + wave * 32;
  int qbaseB = qbaseA + 16;

  const unsigned short* qpA = &qkv[(rowbase + qbaseA + fr) * NQKV + h * 64 + fg * 8];
  const unsigned short* qpB = &qkv[(rowbase + qbaseB + fr) * NQKV + h * 64 + fg * 8];
  bf16x8 qfA0 = *(const bf16x8*)(qpA);
  bf16x8 qfA1 = *(const bf16x8*)(qpA + 32);
  bf16x8 qfB0 = *(const bf16x8*)(qpB);
  bf16x8 qfB1 = *(const bf16x8*)(qpB + 32);

  // staging source col-bytes (inverse swizzle; 512-thread maps):
  // K: rows p*64 + (t>>3), granule t&7 of 128B row  -> row&7 == (t>>3)&7
  // V: rows p*32 + (t>>4), granule t&15 of 256B row -> row&7 == (t>>4)&7
  int kcb = ((t & 7) * 16) ^ (((t >> 3) & 7) << 4);
  int vcb = ((t & 15) * 16) ^ (((t >> 4) & 7) << 4);

  const char* kgb = (const char*)qkv;
  const char* vgb = (const char*)vT;
  long ksrc0 = ((rowbase) * (long)NQKV + KOFF + (long)g * 64) * 2;
  long vsrc0 = (((long)(b * 512 + g * 64)) * LSEQ) * 2;

  auto stageK = [&](int kbase) {
    #pragma unroll
    for (int p = 0; p < 2; p++) {
      int krow = p * 64 + (t >> 3);
      gload_lds16(kgb + ksrc0 + (long)(kbase + krow) * (NQKV * 2) + kcb,
                  KT + p * 8192 + t * 16);
    }
  };
  auto stageV = [&](int kbase, char* dst) {
    #pragma unroll
    for (int p = 0; p < 2; p++) {
      int vrow = p * 32 + (t >> 4);
      gload_lds16(vgb + vsrc0 + (long)vrow * (LSEQ * 2) + kbase * 2 + vcb,
                  dst + p * 8192 + t * 16);
    }
  };

  stageK(0);
  stageV(0, VT2[0]);

  f32x4 poA[4] = {}, poB[4] = {};
  f32x4 lfA = {}, lfB = {};           // MFMA-accumulated row-sums of P (denominator)
  bf16x8 onesv;
  #pragma unroll
  for (int i = 0; i < 8; i++) onesv[i] = (__bf16)1.0f;

  int sw8 = (fr & 7) << 4;
  int ktLast = 2 * qblk + 1;

  for (int kt = 0; kt <= ktLast; kt++) {
    int kbase = kt * 128;
    __syncthreads();   // B1: staged K/V landed; all waves' prev-iter LDS reads done

    // V restage WAR-safe at B1 (prev PV readers of this buffer synced); full-iter cover
    if (kt < ktLast) stageV(kbase + 128, VT2[(kt + 1) & 1]);

    bool active = (kbase < qbaseA + 32);   // wave's q rows intersect this k-tile
    f32x4 stA[8], stB[8];
    if (active) {
      __builtin_amdgcn_s_setprio(1);
      #pragma unroll
      for (int s = 0; s < 8; s++) {
        const char* kr = KT + ((s * 16 + fr) << 7);
        bf16x8 kf0 = *(const bf16x8*)(kr + ((fg * 16) ^ sw8));
        bf16x8 kf1 = *(const bf16x8*)(kr + ((fg * 16 + 64) ^ sw8));
        f32x4 a = {};
        a = __builtin_amdgcn_mfma_f32_16x16x32_bf16(kf0, qfA0, a, 0, 0, 0);
        a = __builtin_amdgcn_mfma_f32_16x16x32_bf16(kf1, qfA1, a, 0, 0, 0);
        stA[s] = a;
        f32x4 c = {};
        c = __builtin_amdgcn_mfma_f32_16x16x32_bf16(kf0, qfB0, c, 0, 0, 0);
        c = __builtin_amdgcn_mfma_f32_16x16x32_bf16(kf1, qfB1, c, 0, 0, 0);
        stB[s] = c;
      }
      __builtin_amdgcn_s_setprio(0);
    }
    __syncthreads();   // B2: all waves' K ds_reads retired -> K restage safe

    if (kt < ktLast) stageK(kbase + 128);   // lands by next B1; softmax+PV cover

    if (active) {
      if (kbase + 127 > qbaseA) {   // wave-local diagonal tile: causal mask
        #pragma unroll
        for (int s = 0; s < 8; s++) {
          #pragma unroll
          for (int r = 0; r < 4; r++) {
            int kp = kbase + s * 16 + fg * 4 + r;
            if (kp > qbaseA + fr) stA[s][r] = -1e30f;
            if (kp > qbaseB + fr) stB[s][r] = -1e30f;
          }
        }
      }

      // softmax (static-max, pre-scaled exp2 domain) + register-only bf16 pack.
      bf16x8 paA[4], paB[4];
      #pragma unroll
      for (int km = 0; km < 4; km++) {
        bf16x8 pa, pb;
        #pragma unroll
        for (int r = 0; r < 4; r++) {
          pa[r]     = (__bf16)exp2f(stA[2 * km][r]);
          pa[r + 4] = (__bf16)exp2f(stA[2 * km + 1][r]);
          pb[r]     = (__bf16)exp2f(stB[2 * km][r]);
          pb[r + 4] = (__bf16)exp2f(stB[2 * km + 1][r]);
        }
        paA[km] = pa;
        paB[km] = pb;
      }

      const char* Vb = VT2[kt & 1];
      __builtin_amdgcn_s_setprio(1);
      #pragma unroll
      for (int km = 0; km < 4; km++) {
        lfA = __builtin_amdgcn_mfma_f32_16x16x32_bf16(paA[km], onesv, lfA, 0, 0, 0);
        lfB = __builtin_amdgcn_mfma_f32_16x16x32_bf16(paB[km], onesv, lfB, 0, 0, 0);
        #pragma unroll
        for (int dt = 0; dt < 4; dt++) {
          const char* vr = Vb + ((dt * 16 + fr) << 8);
          bf16x8 vf = *(const bf16x8*)(vr + ((km * 64 + fg * 16) ^ sw8));
          poA[dt] = __builtin_amdgcn_mfma_f32_16x16x32_bf16(paA[km], vf, poA[dt], 0, 0, 0);
          poB[dt] = __builtin_amdgcn_mfma_f32_16x16x32_bf16(paB[km], vf, poB[dt], 0, 0, 0);
        }
      }
      __builtin_amdgcn_s_setprio(0);
    }
    // no trailing barrier: next B1 orders LDS reads vs. restaging
  }

  // denominator is lane-local: lf[r] = l for q = fg*4+r (identical on every lane's col)
  #pragma unroll
  for (int r = 0; r < 4; r++) {
    float liA = 1.0f / lfA[r];
    float liB = 1.0f / lfB[r];
    #pragma unroll
    for (int dt = 0; dt < 4; dt++) {
      attn[(rowbase + qbaseA + fg * 4 + r) * DIM + h * 64 + dt * 16 + fr] = f2bf(poA[dt][r] * liA);
      attn[(rowbase + qbaseB + fg * 4 + r) * DIM + h * 64 + dt * 16 + fr] = f2bf(poB[dt][r] * liB);
    }
  }
}

extern "C" void kernel_launch(void* const* d_in, const int* in_sizes, int n_in,
                              void* d_out, int out_size, void* d_ws, size_t ws_size,
                              hipStream_t stream) {
  const float* x  = (const float*)d_in[0];
  const float* wq = (const float*)d_in[1];
  const float* wk = (const float*)d_in[2];
  const float* wv = (const float*)d_in[3];
  const float* wo = (const float*)d_in[4];

  char* ws = (char*)d_ws;
  unsigned short* xb    = (unsigned short*)(ws);                 // 16.78 MB (reused as vT later)
  unsigned short* wqkvT = (unsigned short*)(ws + 16777216);      // 12.58 MB [3072][2048]
  unsigned short* woT   = (unsigned short*)(ws + 29360128);      //  8.39 MB [2048][2048]
  unsigned short* qkv   = (unsigned short*)(ws + 37748736);      // 25.17 MB [4096][3072]
  unsigned short* attn  = (unsigned short*)(ws + 62914560);      // 16.78 MB [4096][2048]
  float* cosT           = (float*)(ws + 79691776);               // 256 KB
  float* sinT           = (float*)(ws + 79953920);               // 256 KB
  unsigned short* vT    = xb;                                    // alias: xb dead after QKV GEMM

  const float C2 = 0.125f * 1.44269504f;   // 1/sqrt(64) * log2(e), folded into wq

  k_cvt_x<<<8192, 256, 0, stream>>>(x, xb, M_ROWS * DIM / 4);
  dim3 tb(32, 8);
  // fused weight transposes: one launch, 4 z-sections
  k_transpose_all<<<dim3(64, 64, 4), tb, 0, stream>>>(wq, wk, wv, wo, wqkvT, woT, C2);
  k_rope_table<<<(LSEQ*32)/256, 256, 0, stream>>>(cosT, sinT);

  // QKV: 128^2 BK=64, 512 threads / 8 waves (r13-verified) + fused RoPE
  k_gemm_bt<true, true><<<dim3(M_ROWS/128, NQKV/128), 512, 0, stream>>>(
      xb, wqkvT, qkv, M_ROWS, NQKV, DIM, cosT, sinT);
  k_transpose_v<<<dim3(16, 64, 2), tb, 0, stream>>>(qkv, vT);
  // flash: 8-wave blocks, 256 q-rows/block, shared K/V staging (grid 512)
  k_flash_attn15<<<512, 512, 0, stream>>>(qkv, vT, attn);
  // WO: r11/r13 128^2 dbuf single-barrier pipeline, 512 threads
  k_gemm_db<<<dim3(M_ROWS/128, DIM/128), 512, 0, stream>>>(
      attn, woT, (float*)d_out, M_ROWS, DIM, DIM);
}

// Round 16
// 217.503 us; speedup vs baseline: 1.3835x; 1.3835x over previous
//
#include <hip/hip_runtime.h>
#include <stdint.h>

#define DIM   2048
#define LSEQ  2048
#define BATCH 2
#define NH    32
#define NKV   8
#define HD    64
#define M_ROWS (BATCH*LSEQ)       // 4096
#define NQKV  (DIM + 2*NKV*HD)    // 3072
#define KOFF  DIM                 // 2048
#define VOFF  (DIM + NKV*HD)      // 2560

typedef __attribute__((ext_vector_type(8))) __bf16 bf16x8;
typedef __attribute__((ext_vector_type(8))) unsigned short u16x8;
typedef __attribute__((ext_vector_type(4))) float f32x4;

// hardware RNE f32->bf16 (harness-verified rounds 2-15)
__device__ __forceinline__ unsigned short f2bf(float f) {
  union { __bf16 h; unsigned short u; } v;
  v.h = (__bf16)f;
  return v.u;
}
__device__ __forceinline__ float bf2f(unsigned short h) {
  union { unsigned u; float f; } v; v.u = ((unsigned)h) << 16;
  return v.f;
}

__device__ __forceinline__ void gload_lds16(const void* g, void* l) {
  __builtin_amdgcn_global_load_lds(
      (__attribute__((address_space(1))) unsigned int*)g,
      (__attribute__((address_space(3))) unsigned int*)l, 16, 0, 0);
}

// ---------------- fp32 -> bf16 convert (vectorized) ----------------
__global__ void k_cvt_x(const float* __restrict__ in, unsigned short* __restrict__ out, int n4) {
  int i = blockIdx.x * blockDim.x + threadIdx.x;
  if (i >= n4) return;
  float4 v = ((const float4*)in)[i];
  ushort4 o;
  o.x = f2bf(v.x); o.y = f2bf(v.y); o.z = f2bf(v.z); o.w = f2bf(v.w);
  ((ushort4*)out)[i] = o;
}

// ---------------- fused weight transposes: 4 launches -> 1 (z-sectioned) ----------------
__global__ void k_transpose_all(const float* __restrict__ wq, const float* __restrict__ wk,
                                const float* __restrict__ wv, const float* __restrict__ wo,
                                unsigned short* __restrict__ wqkvT,
                                unsigned short* __restrict__ woT, float C2) {
  __shared__ float tile[32][33];
  int sec = blockIdx.z;
  const float* in; unsigned short* out; int N; float scale = 1.0f;
  if (sec == 0)      { in = wq; out = wqkvT;                     N = DIM; scale = C2; }
  else if (sec == 1) { in = wk; out = wqkvT + (long)2048 * 2048; N = 512; }
  else if (sec == 2) { in = wv; out = wqkvT + (long)2560 * 2048; N = 512; }
  else               { in = wo; out = woT;                       N = DIM; }
  int n0 = blockIdx.x * 32;
  if (n0 >= N) return;
  int k0 = blockIdx.y * 32;
  int tx = threadIdx.x, ty = threadIdx.y;
  #pragma unroll
  for (int i = ty; i < 32; i += 8)
    tile[i][tx] = in[(long)(k0 + i) * N + n0 + tx];
  __syncthreads();
  #pragma unroll
  for (int i = ty; i < 32; i += 8)
    out[(long)(n0 + i) * DIM + k0 + tx] = f2bf(scale * tile[tx][i]);
}

// ---------------- transpose V section of qkv -> vT, k-PERMUTED columns ----------------
// Column position e holds original k = tx with e = 8*((tx>>2)&3) + 4*(tx>>4) + (tx&3),
// matching flash's in-register-P A-fragment k-order (round 6/7, verified).
__global__ void k_transpose_v(const unsigned short* __restrict__ qkv,
                              unsigned short* __restrict__ vT) {
  __shared__ unsigned short tile[32][33];
  int c0 = blockIdx.x * 32;   // within 512 (= g*64+d)
  int l0 = blockIdx.y * 32;
  int b  = blockIdx.z;
  int tx = threadIdx.x, ty = threadIdx.y;
  #pragma unroll
  for (int i = ty; i < 32; i += 8)
    tile[i][tx] = qkv[((long)b * LSEQ + l0 + i) * NQKV + VOFF + c0 + tx];
  __syncthreads();
  int e = 8 * ((tx >> 2) & 3) + 4 * (tx >> 4) + (tx & 3);
  #pragma unroll
  for (int i = ty; i < 32; i += 8)
    vT[((long)b * 512 + c0 + i) * LSEQ + l0 + e] = tile[tx][i];
}

// ---------------- RoPE tables ----------------
__global__ void k_rope_table(float* __restrict__ cosT, float* __restrict__ sinT) {
  int i = blockIdx.x * 256 + threadIdx.x;  // < LSEQ*32
  int t = i >> 5, j = i & 31;
  float inv = powf(10000.0f, -(float)j / 32.0f);
  float fr = (float)t * inv;
  cosT[i] = cosf(fr);
  sinT[i] = sinf(fr);
}

// ---------------- GEMM v8 (QKV): 128^2 tile, BK=64, 512 threads / 8 waves (r13, verified) ----------------
template<bool BF16OUT, bool ROPE>
__global__ __launch_bounds__(512, 4) void k_gemm_bt(
    const unsigned short* __restrict__ A, const unsigned short* __restrict__ Bt,
    void* __restrict__ Cv, int M, int N, int K,
    const float* __restrict__ cosT, const float* __restrict__ sinT) {
  __shared__ __align__(16) char AsB[16384];   // [128 rows][128B], swizzled
  __shared__ __align__(16) char BsB[16384];
  int t = threadIdx.x;
  int lane = t & 63, wave = t >> 6;        // 0..7
  int fr = lane & 15, fg = lane >> 4;
  int wm = wave >> 1, wn = wave & 1;       // 4M x 2N quadrants: 32 rows x 64 cols
  long rowA = (long)blockIdx.x * 128;
  long rowB = (long)blockIdx.y * 128;
  long K2 = (long)K * 2;

  int scol = ((t & 7) * 16) ^ (((t >> 3) & 7) << 4);
  const char* ApB = (const char*)A  + (rowA + (t >> 3)) * K2 + scol;
  const char* BpB = (const char*)Bt + (rowB + (t >> 3)) * K2 + scol;

  f32x4 acc[2][4] = {};
  int sw8 = (fr & 7) << 4;

  for (int kt = 0; kt < K; kt += 64) {
    #pragma unroll
    for (int p = 0; p < 2; p++) {
      gload_lds16(ApB + (long)(p * 64) * K2 + kt * 2, AsB + p * 8192 + t * 16);
      gload_lds16(BpB + (long)(p * 64) * K2 + kt * 2, BsB + p * 8192 + t * 16);
    }
    __syncthreads();
    #pragma unroll
    for (int ks = 0; ks < 2; ks++) {
      bf16x8 af[2], bfv[4];
      #pragma unroll
      for (int i = 0; i < 2; i++)
        af[i] = *(const bf16x8*)(AsB + (wm * 32 + i * 16 + fr) * 128 + ((ks * 64 + fg * 16) ^ sw8));
      #pragma unroll
      for (int j = 0; j < 4; j++)
        bfv[j] = *(const bf16x8*)(BsB + (wn * 64 + j * 16 + fr) * 128 + ((ks * 64 + fg * 16) ^ sw8));
      #pragma unroll
      for (int i = 0; i < 2; i++) {
        #pragma unroll
        for (int j = 0; j < 4; j++)
          acc[i][j] = __builtin_amdgcn_mfma_f32_16x16x32_bf16(af[i], bfv[j], acc[i][j], 0, 0, 0);
      }
    }
    __syncthreads();
  }

  long colbase = rowB + wn * 64;
  bool rope_sec = ROPE && (colbase < VOFF);   // Q or K head (col < 2560); wave-uniform
  #pragma unroll
  for (int i = 0; i < 2; i++) {
    #pragma unroll
    for (int r = 0; r < 4; r++) {
      long row = rowA + wm * 32 + i * 16 + fg * 4 + r;
      if (ROPE && rope_sec) {
        int tpos = (int)(row & (LSEQ - 1));
        #pragma unroll
        for (int j = 0; j < 2; j++) {   // pair (d = j*16+fr, d+32 = (j+2)*16+fr)
          int jj = j * 16 + fr;
          float c = cosT[tpos * 32 + jj];
          float s = sinT[tpos * 32 + jj];
          float lo = acc[i][j][r], hi = acc[i][j + 2][r];
          ((unsigned short*)Cv)[row * N + colbase + j * 16 + fr]       = f2bf(lo * c - hi * s);
          ((unsigned short*)Cv)[row * N + colbase + (j + 2) * 16 + fr] = f2bf(hi * c + lo * s);
        }
      } else {
        #pragma unroll
        for (int j = 0; j < 4; j++) {
          long col = colbase + j * 16 + fr;
          if (BF16OUT) ((unsigned short*)Cv)[row * N + col] = f2bf(acc[i][j][r]);
          else         ((float*)Cv)[row * N + col] = acc[i][j][r];
        }
      }
    }
  }
}

// ---------------- GEMM v9 (WO): 128^2 dbuf single-barrier pipeline, 512 threads (r13, verified) ----------------
__global__ __launch_bounds__(512, 4) void k_gemm_db(
    const unsigned short* __restrict__ A, const unsigned short* __restrict__ Bt,
    float* __restrict__ Cv, int M, int N, int K) {
  __shared__ __align__(16) char AsB[2][16384];   // [buf][128 rows][128B], swizzled
  __shared__ __align__(16) char BsB[2][16384];
  int t = threadIdx.x;
  int lane = t & 63, wave = t >> 6;
  int fr = lane & 15, fg = lane >> 4;
  int wm = wave >> 1, wn = wave & 1;       // 4M x 2N quadrants: 32 rows x 64 cols
  long rowA = (long)blockIdx.x * 128;
  long rowB = (long)blockIdx.y * 128;
  long K2 = (long)K * 2;

  int scol = ((t & 7) * 16) ^ (((t >> 3) & 7) << 4);
  const char* ApB = (const char*)A  + (rowA + (t >> 3)) * K2 + scol;
  const char* BpB = (const char*)Bt + (rowB + (t >> 3)) * K2 + scol;

  auto stage = [&](int kt, int bi) {   // kt in 64-elem tiles; 4 loads/thread
    #pragma unroll
    for (int p = 0; p < 2; p++) {
      gload_lds16(ApB + (long)(p * 64) * K2 + (long)kt * 128, AsB[bi] + p * 8192 + t * 16);
      gload_lds16(BpB + (long)(p * 64) * K2 + (long)kt * 128, BsB[bi] + p * 8192 + t * 16);
    }
  };

  f32x4 acc[2][4] = {};
  int sw8 = (fr & 7) << 4;
  int NT = K >> 6;

  stage(0, 0);
  for (int kt = 0; kt < NT; kt++) {
    int cur = kt & 1;
    asm volatile("s_waitcnt vmcnt(0)" ::: "memory");
    __builtin_amdgcn_s_barrier();
    __builtin_amdgcn_sched_barrier(0);
    const char* Ac = AsB[cur];
    const char* Bc = BsB[cur];
    #pragma unroll
    for (int ks = 0; ks < 2; ks++) {
      bf16x8 af[2], bfv[4];
      #pragma unroll
      for (int i = 0; i < 2; i++)
        af[i] = *(const bf16x8*)(Ac + (wm * 32 + i * 16 + fr) * 128 + ((ks * 64 + fg * 16) ^ sw8));
      #pragma unroll
      for (int j = 0; j < 4; j++)
        bfv[j] = *(const bf16x8*)(Bc + (wn * 64 + j * 16 + fr) * 128 + ((ks * 64 + fg * 16) ^ sw8));
      if (ks == 0 && kt + 1 < NT) stage(kt + 1, cur ^ 1);   // issue under reads+MFMA
      #pragma unroll
      for (int i = 0; i < 2; i++) {
        #pragma unroll
        for (int j = 0; j < 4; j++)
          acc[i][j] = __builtin_amdgcn_mfma_f32_16x16x32_bf16(af[i], bfv[j], acc[i][j], 0, 0, 0);
      }
    }
  }

  #pragma unroll
  for (int i = 0; i < 2; i++) {
    #pragma unroll
    for (int j = 0; j < 4; j++) {
      #pragma unroll
      for (int r = 0; r < 4; r++) {
        long row = rowA + wm * 32 + i * 16 + fg * 4 + r;
        long col = rowB + wn * 64 + j * 16 + fr;
        Cv[row * N + col] = acc[i][j][r];
      }
    }
  }
}

// ---------------- flash attention v19: 8-wave shared staging, UNCONDITIONAL compute ----------------
// Round-16: v18's active-guard split stA/stB liveness across barriers inside divergent
// control flow -> compiler spilled the arrays to scratch (VGPR 84->64, WRITE_SIZE
// 17->362MB -- the rule-#20 signature, same as round 6's union bug). Fix: remove the
// guard entirely; every wave computes every tile (straight-line loop body, CFG identical
// to the verified v17). Correctness: tiles fully above a wave's rows hit the causal mask
// (kbase+127 > qbaseA covers them; all kp > qbase+fr) -> st = -1e30 -> P = exp2(-1e30)
// = 0 -> contributes nothing to po/lf. Cost: waves 0-3 compute one fully-masked tile
// (~+6% MFMA) -- cheap vs 362MB scratch. Keeps v18's wins: shared K/V staging (4
// gloads/thread/iter), 512 threads -> 16 waves/CU, ones-MFMA denominator.
__global__ __launch_bounds__(512, 4) void k_flash_attn16(
    const unsigned short* __restrict__ qkv, const unsigned short* __restrict__ vT,
    unsigned short* __restrict__ attn) {
  int g0 = (int)blockIdx.x;
  int hb = g0 & 63;
  int h = hb & 31, b = hb >> 5;
  int qblk = 7 - (g0 >> 6);           // heavy blocks first (backfill smooths the tail)
  int g = h >> 2;
  int t = threadIdx.x, lane = t & 63, wave = t >> 6;   // wave 0..7
  int fr = lane & 15, fg = lane >> 4;

  __shared__ __align__(16) char KT[16384];              // 16KB: K tile [128 rows][128B], swz
  __shared__ __align__(16) char VT2[2][16384];          // 32KB: V tile [64 rows][256B], swz, dbuf
  long rowbase = (long)b * LSEQ;

  int qbaseA = qblk * 256 + wave * 32;
  int qbaseB = qbaseA + 16;

  const unsigned short* qpA = &qkv[(rowbase + qbaseA + fr) * NQKV + h * 64 + fg * 8];
  const unsigned short* qpB = &qkv[(rowbase + qbaseB + fr) * NQKV + h * 64 + fg * 8];
  bf16x8 qfA0 = *(const bf16x8*)(qpA);
  bf16x8 qfA1 = *(const bf16x8*)(qpA + 32);
  bf16x8 qfB0 = *(const bf16x8*)(qpB);
  bf16x8 qfB1 = *(const bf16x8*)(qpB + 32);

  // staging source col-bytes (inverse swizzle; 512-thread maps):
  // K: rows p*64 + (t>>3), granule t&7 of 128B row  -> row&7 == (t>>3)&7
  // V: rows p*32 + (t>>4), granule t&15 of 256B row -> row&7 == (t>>4)&7
  int kcb = ((t & 7) * 16) ^ (((t >> 3) & 7) << 4);
  int vcb = ((t & 15) * 16) ^ (((t >> 4) & 7) << 4);

  const char* kgb = (const char*)qkv;
  const char* vgb = (const char*)vT;
  long ksrc0 = ((rowbase) * (long)NQKV + KOFF + (long)g * 64) * 2;
  long vsrc0 = (((long)(b * 512 + g * 64)) * LSEQ) * 2;

  auto stageK = [&](int kbase) {
    #pragma unroll
    for (int p = 0; p < 2; p++) {
      int krow = p * 64 + (t >> 3);
      gload_lds16(kgb + ksrc0 + (long)(kbase + krow) * (NQKV * 2) + kcb,
                  KT + p * 8192 + t * 16);
    }
  };
  auto stageV = [&](int kbase, char* dst) {
    #pragma unroll
    for (int p = 0; p < 2; p++) {
      int vrow = p * 32 + (t >> 4);
      gload_lds16(vgb + vsrc0 + (long)vrow * (LSEQ * 2) + kbase * 2 + vcb,
                  dst + p * 8192 + t * 16);
    }
  };

  stageK(0);
  stageV(0, VT2[0]);

  f32x4 poA[4] = {}, poB[4] = {};
  f32x4 lfA = {}, lfB = {};           // MFMA-accumulated row-sums of P (denominator)
  bf16x8 onesv;
  #pragma unroll
  for (int i = 0; i < 8; i++) onesv[i] = (__bf16)1.0f;

  int sw8 = (fr & 7) << 4;
  int ktLast = 2 * qblk + 1;

  for (int kt = 0; kt <= ktLast; kt++) {
    int kbase = kt * 128;
    __syncthreads();   // B1: staged K/V landed; all waves' prev-iter LDS reads done

    // V restage WAR-safe at B1 (prev PV readers of this buffer synced); full-iter cover
    if (kt < ktLast) stageV(kbase + 128, VT2[(kt + 1) & 1]);

    f32x4 stA[8], stB[8];
    __builtin_amdgcn_s_setprio(1);
    #pragma unroll
    for (int s = 0; s < 8; s++) {
      const char* kr = KT + ((s * 16 + fr) << 7);
      bf16x8 kf0 = *(const bf16x8*)(kr + ((fg * 16) ^ sw8));
      bf16x8 kf1 = *(const bf16x8*)(kr + ((fg * 16 + 64) ^ sw8));
      f32x4 a = {};
      a = __builtin_amdgcn_mfma_f32_16x16x32_bf16(kf0, qfA0, a, 0, 0, 0);
      a = __builtin_amdgcn_mfma_f32_16x16x32_bf16(kf1, qfA1, a, 0, 0, 0);
      stA[s] = a;
      f32x4 c = {};
      c = __builtin_amdgcn_mfma_f32_16x16x32_bf16(kf0, qfB0, c, 0, 0, 0);
      c = __builtin_amdgcn_mfma_f32_16x16x32_bf16(kf1, qfB1, c, 0, 0, 0);
      stB[s] = c;
    }
    __builtin_amdgcn_s_setprio(0);
    __syncthreads();   // B2: all waves' K ds_reads retired -> K restage safe

    if (kt < ktLast) stageK(kbase + 128);   // lands by next B1; softmax+PV cover

    if (kbase + 127 > qbaseA) {   // covers wave-local diagonal AND fully-above tiles
      #pragma unroll
      for (int s = 0; s < 8; s++) {
        #pragma unroll
        for (int r = 0; r < 4; r++) {
          int kp = kbase + s * 16 + fg * 4 + r;
          if (kp > qbaseA + fr) stA[s][r] = -1e30f;
          if (kp > qbaseB + fr) stB[s][r] = -1e30f;
        }
      }
    }

    // softmax (static-max, pre-scaled exp2 domain) + register-only bf16 pack.
    // A-frag slot (fg, j): j=r -> k32 = 4*fg + r ; j=4+r -> k32 = 16 + 4*fg + r.
    bf16x8 paA[4], paB[4];
    #pragma unroll
    for (int km = 0; km < 4; km++) {
      bf16x8 pa, pb;
      #pragma unroll
      for (int r = 0; r < 4; r++) {
        pa[r]     = (__bf16)exp2f(stA[2 * km][r]);
        pa[r + 4] = (__bf16)exp2f(stA[2 * km + 1][r]);
        pb[r]     = (__bf16)exp2f(stB[2 * km][r]);
        pb[r + 4] = (__bf16)exp2f(stB[2 * km + 1][r]);
      }
      paA[km] = pa;
      paB[km] = pb;
    }

    const char* Vb = VT2[kt & 1];
    __builtin_amdgcn_s_setprio(1);
    #pragma unroll
    for (int km = 0; km < 4; km++) {
      lfA = __builtin_amdgcn_mfma_f32_16x16x32_bf16(paA[km], onesv, lfA, 0, 0, 0);
      lfB = __builtin_amdgcn_mfma_f32_16x16x32_bf16(paB[km], onesv, lfB, 0, 0, 0);
      #pragma unroll
      for (int dt = 0; dt < 4; dt++) {
        const char* vr = Vb + ((dt * 16 + fr) << 8);
        bf16x8 vf = *(const bf16x8*)(vr + ((km * 64 + fg * 16) ^ sw8));
        poA[dt] = __builtin_amdgcn_mfma_f32_16x16x32_bf16(paA[km], vf, poA[dt], 0, 0, 0);
        poB[dt] = __builtin_amdgcn_mfma_f32_16x16x32_bf16(paB[km], vf, poB[dt], 0, 0, 0);
      }
    }
    __builtin_amdgcn_s_setprio(0);
    // no trailing barrier: next B1 orders LDS reads vs. restaging
  }

  // denominator is lane-local: lf[r] = l for q = fg*4+r (identical on every lane's col)
  #pragma unroll
  for (int r = 0; r < 4; r++) {
    float liA = 1.0f / lfA[r];
    float liB = 1.0f / lfB[r];
    #pragma unroll
    for (int dt = 0; dt < 4; dt++) {
      attn[(rowbase + qbaseA + fg * 4 + r) * DIM + h * 64 + dt * 16 + fr] = f2bf(poA[dt][r] * liA);
      attn[(rowbase + qbaseB + fg * 4 + r) * DIM + h * 64 + dt * 16 + fr] = f2bf(poB[dt][r] * liB);
    }
  }
}

extern "C" void kernel_launch(void* const* d_in, const int* in_sizes, int n_in,
                              void* d_out, int out_size, void* d_ws, size_t ws_size,
                              hipStream_t stream) {
  const float* x  = (const float*)d_in[0];
  const float* wq = (const float*)d_in[1];
  const float* wk = (const float*)d_in[2];
  const float* wv = (const float*)d_in[3];
  const float* wo = (const float*)d_in[4];

  char* ws = (char*)d_ws;
  unsigned short* xb    = (unsigned short*)(ws);                 // 16.78 MB (reused as vT later)
  unsigned short* wqkvT = (unsigned short*)(ws + 16777216);      // 12.58 MB [3072][2048]
  unsigned short* woT   = (unsigned short*)(ws + 29360128);      //  8.39 MB [2048][2048]
  unsigned short* qkv   = (unsigned short*)(ws + 37748736);      // 25.17 MB [4096][3072]
  unsigned short* attn  = (unsigned short*)(ws + 62914560);      // 16.78 MB [4096][2048]
  float* cosT           = (float*)(ws + 79691776);               // 256 KB
  float* sinT           = (float*)(ws + 79953920);               // 256 KB
  unsigned short* vT    = xb;                                    // alias: xb dead after QKV GEMM

  const float C2 = 0.125f * 1.44269504f;   // 1/sqrt(64) * log2(e), folded into wq

  k_cvt_x<<<8192, 256, 0, stream>>>(x, xb, M_ROWS * DIM / 4);
  dim3 tb(32, 8);
  // fused weight transposes: one launch, 4 z-sections
  k_transpose_all<<<dim3(64, 64, 4), tb, 0, stream>>>(wq, wk, wv, wo, wqkvT, woT, C2);
  k_rope_table<<<(LSEQ*32)/256, 256, 0, stream>>>(cosT, sinT);

  // QKV: 128^2 BK=64, 512 threads / 8 waves (r13-verified) + fused RoPE
  k_gemm_bt<true, true><<<dim3(M_ROWS/128, NQKV/128), 512, 0, stream>>>(
      xb, wqkvT, qkv, M_ROWS, NQKV, DIM, cosT, sinT);
  k_transpose_v<<<dim3(16, 64, 2), tb, 0, stream>>>(qkv, vT);
  // flash: 8-wave blocks, 256 q-rows/block, shared K/V staging, unconditional compute
  k_flash_attn16<<<512, 512, 0, stream>>>(qkv, vT, attn);
  // WO: r11/r13 128^2 dbuf single-barrier pipeline, 512 threads
  k_gemm_db<<<dim3(M_ROWS/128, DIM/128), 512, 0, stream>>>(
      attn, woT, (float*)d_out, M_ROWS, DIM, DIM);
}

// Round 17
// 178.631 us; speedup vs baseline: 1.6845x; 1.2176x over previous
//
#include <hip/hip_runtime.h>
#include <stdint.h>

#define DIM   2048
#define LSEQ  2048
#define BATCH 2
#define NH    32
#define NKV   8
#define HD    64
#define M_ROWS (BATCH*LSEQ)       // 4096
#define NQKV  (DIM + 2*NKV*HD)    // 3072
#define KOFF  DIM                 // 2048
#define VOFF  (DIM + NKV*HD)      // 2560

typedef __attribute__((ext_vector_type(8))) __bf16 bf16x8;
typedef __attribute__((ext_vector_type(8))) unsigned short u16x8;
typedef __attribute__((ext_vector_type(4))) float f32x4;

// hardware RNE f32->bf16 (harness-verified rounds 2-16)
__device__ __forceinline__ unsigned short f2bf(float f) {
  union { __bf16 h; unsigned short u; } v;
  v.h = (__bf16)f;
  return v.u;
}
__device__ __forceinline__ float bf2f(unsigned short h) {
  union { unsigned u; float f; } v; v.u = ((unsigned)h) << 16;
  return v.f;
}

__device__ __forceinline__ void gload_lds16(const void* g, void* l) {
  __builtin_amdgcn_global_load_lds(
      (__attribute__((address_space(1))) unsigned int*)g,
      (__attribute__((address_space(3))) unsigned int*)l, 16, 0, 0);
}

// ---------------- fp32 -> bf16 convert (vectorized) ----------------
__global__ void k_cvt_x(const float* __restrict__ in, unsigned short* __restrict__ out, int n4) {
  int i = blockIdx.x * blockDim.x + threadIdx.x;
  if (i >= n4) return;
  float4 v = ((const float4*)in)[i];
  ushort4 o;
  o.x = f2bf(v.x); o.y = f2bf(v.y); o.z = f2bf(v.z); o.w = f2bf(v.w);
  ((ushort4*)out)[i] = o;
}

// ---------------- fused weight transposes: 4 launches -> 1 (z-sectioned) ----------------
__global__ void k_transpose_all(const float* __restrict__ wq, const float* __restrict__ wk,
                                const float* __restrict__ wv, const float* __restrict__ wo,
                                unsigned short* __restrict__ wqkvT,
                                unsigned short* __restrict__ woT, float C2) {
  __shared__ float tile[32][33];
  int sec = blockIdx.z;
  const float* in; unsigned short* out; int N; float scale = 1.0f;
  if (sec == 0)      { in = wq; out = wqkvT;                     N = DIM; scale = C2; }
  else if (sec == 1) { in = wk; out = wqkvT + (long)2048 * 2048; N = 512; }
  else if (sec == 2) { in = wv; out = wqkvT + (long)2560 * 2048; N = 512; }
  else               { in = wo; out = woT;                       N = DIM; }
  int n0 = blockIdx.x * 32;
  if (n0 >= N) return;
  int k0 = blockIdx.y * 32;
  int tx = threadIdx.x, ty = threadIdx.y;
  #pragma unroll
  for (int i = ty; i < 32; i += 8)
    tile[i][tx] = in[(long)(k0 + i) * N + n0 + tx];
  __syncthreads();
  #pragma unroll
  for (int i = ty; i < 32; i += 8)
    out[(long)(n0 + i) * DIM + k0 + tx] = f2bf(scale * tile[tx][i]);
}

// ---------------- transpose V section of qkv -> vT, k-PERMUTED columns ----------------
// Column position e holds original k = tx with e = 8*((tx>>2)&3) + 4*(tx>>4) + (tx&3),
// matching flash's in-register-P A-fragment k-order (round 6/7, verified).
__global__ void k_transpose_v(const unsigned short* __restrict__ qkv,
                              unsigned short* __restrict__ vT) {
  __shared__ unsigned short tile[32][33];
  int c0 = blockIdx.x * 32;   // within 512 (= g*64+d)
  int l0 = blockIdx.y * 32;
  int b  = blockIdx.z;
  int tx = threadIdx.x, ty = threadIdx.y;
  #pragma unroll
  for (int i = ty; i < 32; i += 8)
    tile[i][tx] = qkv[((long)b * LSEQ + l0 + i) * NQKV + VOFF + c0 + tx];
  __syncthreads();
  int e = 8 * ((tx >> 2) & 3) + 4 * (tx >> 4) + (tx & 3);
  #pragma unroll
  for (int i = ty; i < 32; i += 8)
    vT[((long)b * 512 + c0 + i) * LSEQ + l0 + e] = tile[tx][i];
}

// ---------------- RoPE tables ----------------
__global__ void k_rope_table(float* __restrict__ cosT, float* __restrict__ sinT) {
  int i = blockIdx.x * 256 + threadIdx.x;  // < LSEQ*32
  int t = i >> 5, j = i & 31;
  float inv = powf(10000.0f, -(float)j / 32.0f);
  float fr = (float)t * inv;
  cosT[i] = cosf(fr);
  sinT[i] = sinf(fr);
}

// ---------------- GEMM v8 (QKV): 128^2 tile, BK=64, 512 thr / 8 waves + XCD swizzle ----------------
// r13-verified structure; r17 adds the T1 XCD-aware bijective block swizzle (grid %8==0):
// consecutive swizzled ids share an A-panel within one XCD's L2 (FETCH 58MB vs 38MB
// ideal -> panel re-fetch reduction). Pure remap, correctness-free.
template<bool BF16OUT, bool ROPE>
__global__ __launch_bounds__(512, 4) void k_gemm_bt(
    const unsigned short* __restrict__ A, const unsigned short* __restrict__ Bt,
    void* __restrict__ Cv, int M, int N, int K, int nbn,
    const float* __restrict__ cosT, const float* __restrict__ sinT) {
  __shared__ __align__(16) char AsB[16384];   // [128 rows][128B], swizzled
  __shared__ __align__(16) char BsB[16384];
  int t = threadIdx.x;
  int lane = t & 63, wave = t >> 6;        // 0..7
  int fr = lane & 15, fg = lane >> 4;
  int wm = wave >> 1, wn = wave & 1;       // 4M x 2N quadrants: 32 rows x 64 cols
  int nwg = (int)gridDim.x;
  int id = (int)blockIdx.x;
  int swz = (id & 7) * (nwg >> 3) + (id >> 3);   // bijective XCD swizzle
  long rowA = (long)(swz / nbn) * 128;
  long rowB = (long)(swz % nbn) * 128;
  long K2 = (long)K * 2;

  int scol = ((t & 7) * 16) ^ (((t >> 3) & 7) << 4);
  const char* ApB = (const char*)A  + (rowA + (t >> 3)) * K2 + scol;
  const char* BpB = (const char*)Bt + (rowB + (t >> 3)) * K2 + scol;

  f32x4 acc[2][4] = {};
  int sw8 = (fr & 7) << 4;

  for (int kt = 0; kt < K; kt += 64) {
    #pragma unroll
    for (int p = 0; p < 2; p++) {
      gload_lds16(ApB + (long)(p * 64) * K2 + kt * 2, AsB + p * 8192 + t * 16);
      gload_lds16(BpB + (long)(p * 64) * K2 + kt * 2, BsB + p * 8192 + t * 16);
    }
    __syncthreads();
    #pragma unroll
    for (int ks = 0; ks < 2; ks++) {
      bf16x8 af[2], bfv[4];
      #pragma unroll
      for (int i = 0; i < 2; i++)
        af[i] = *(const bf16x8*)(AsB + (wm * 32 + i * 16 + fr) * 128 + ((ks * 64 + fg * 16) ^ sw8));
      #pragma unroll
      for (int j = 0; j < 4; j++)
        bfv[j] = *(const bf16x8*)(BsB + (wn * 64 + j * 16 + fr) * 128 + ((ks * 64 + fg * 16) ^ sw8));
      #pragma unroll
      for (int i = 0; i < 2; i++) {
        #pragma unroll
        for (int j = 0; j < 4; j++)
          acc[i][j] = __builtin_amdgcn_mfma_f32_16x16x32_bf16(af[i], bfv[j], acc[i][j], 0, 0, 0);
      }
    }
    __syncthreads();
  }

  long colbase = rowB + wn * 64;
  bool rope_sec = ROPE && (colbase < VOFF);   // Q or K head (col < 2560); wave-uniform
  #pragma unroll
  for (int i = 0; i < 2; i++) {
    #pragma unroll
    for (int r = 0; r < 4; r++) {
      long row = rowA + wm * 32 + i * 16 + fg * 4 + r;
      if (ROPE && rope_sec) {
        int tpos = (int)(row & (LSEQ - 1));
        #pragma unroll
        for (int j = 0; j < 2; j++) {   // pair (d = j*16+fr, d+32 = (j+2)*16+fr)
          int jj = j * 16 + fr;
          float c = cosT[tpos * 32 + jj];
          float s = sinT[tpos * 32 + jj];
          float lo = acc[i][j][r], hi = acc[i][j + 2][r];
          ((unsigned short*)Cv)[row * N + colbase + j * 16 + fr]       = f2bf(lo * c - hi * s);
          ((unsigned short*)Cv)[row * N + colbase + (j + 2) * 16 + fr] = f2bf(hi * c + lo * s);
        }
      } else {
        #pragma unroll
        for (int j = 0; j < 4; j++) {
          long col = colbase + j * 16 + fr;
          if (BF16OUT) ((unsigned short*)Cv)[row * N + col] = f2bf(acc[i][j][r]);
          else         ((float*)Cv)[row * N + col] = acc[i][j][r];
        }
      }
    }
  }
}

// ---------------- GEMM v9 (WO): 128^2 dbuf single-barrier pipeline + XCD swizzle ----------------
__global__ __launch_bounds__(512, 4) void k_gemm_db(
    const unsigned short* __restrict__ A, const unsigned short* __restrict__ Bt,
    float* __restrict__ Cv, int M, int N, int K, int nbn) {
  __shared__ __align__(16) char AsB[2][16384];   // [buf][128 rows][128B], swizzled
  __shared__ __align__(16) char BsB[2][16384];
  int t = threadIdx.x;
  int lane = t & 63, wave = t >> 6;
  int fr = lane & 15, fg = lane >> 4;
  int wm = wave >> 1, wn = wave & 1;       // 4M x 2N quadrants: 32 rows x 64 cols
  int nwg = (int)gridDim.x;
  int id = (int)blockIdx.x;
  int swz = (id & 7) * (nwg >> 3) + (id >> 3);   // bijective XCD swizzle
  long rowA = (long)(swz / nbn) * 128;
  long rowB = (long)(swz % nbn) * 128;
  long K2 = (long)K * 2;

  int scol = ((t & 7) * 16) ^ (((t >> 3) & 7) << 4);
  const char* ApB = (const char*)A  + (rowA + (t >> 3)) * K2 + scol;
  const char* BpB = (const char*)Bt + (rowB + (t >> 3)) * K2 + scol;

  auto stage = [&](int kt, int bi) {   // kt in 64-elem tiles; 4 loads/thread
    #pragma unroll
    for (int p = 0; p < 2; p++) {
      gload_lds16(ApB + (long)(p * 64) * K2 + (long)kt * 128, AsB[bi] + p * 8192 + t * 16);
      gload_lds16(BpB + (long)(p * 64) * K2 + (long)kt * 128, BsB[bi] + p * 8192 + t * 16);
    }
  };

  f32x4 acc[2][4] = {};
  int sw8 = (fr & 7) << 4;
  int NT = K >> 6;

  stage(0, 0);
  for (int kt = 0; kt < NT; kt++) {
    int cur = kt & 1;
    asm volatile("s_waitcnt vmcnt(0)" ::: "memory");
    __builtin_amdgcn_s_barrier();
    __builtin_amdgcn_sched_barrier(0);
    const char* Ac = AsB[cur];
    const char* Bc = BsB[cur];
    #pragma unroll
    for (int ks = 0; ks < 2; ks++) {
      bf16x8 af[2], bfv[4];
      #pragma unroll
      for (int i = 0; i < 2; i++)
        af[i] = *(const bf16x8*)(Ac + (wm * 32 + i * 16 + fr) * 128 + ((ks * 64 + fg * 16) ^ sw8));
      #pragma unroll
      for (int j = 0; j < 4; j++)
        bfv[j] = *(const bf16x8*)(Bc + (wn * 64 + j * 16 + fr) * 128 + ((ks * 64 + fg * 16) ^ sw8));
      if (ks == 0 && kt + 1 < NT) stage(kt + 1, cur ^ 1);   // issue under reads+MFMA
      #pragma unroll
      for (int i = 0; i < 2; i++) {
        #pragma unroll
        for (int j = 0; j < 4; j++)
          acc[i][j] = __builtin_amdgcn_mfma_f32_16x16x32_bf16(af[i], bfv[j], acc[i][j], 0, 0, 0);
      }
    }
  }

  #pragma unroll
  for (int i = 0; i < 2; i++) {
    #pragma unroll
    for (int j = 0; j < 4; j++) {
      #pragma unroll
      for (int r = 0; r < 4; r++) {
        long row = rowA + wm * 32 + i * 16 + fg * 4 + r;
        long col = rowB + wn * 64 + j * 16 + fr;
        Cv[row * N + col] = acc[i][j][r];
      }
    }
  }
}

// ---------------- flash attention v17 (r14-verified, 64.5us): REVERTED from 8-wave ----------------
// r15/r16's 8-wave shared-staging spilled to scratch both times (wave-dependent causal
// mask defeats the last-iteration peel that keeps v17's stA/stB in registers at 84
// VGPR; 512-thread cap 128 < the resulting ~150 peak). Pre-committed fallback: this
// 4-wave structure is the keeper. Swapped QK (mfma(K,Q)) -> P lane-local; register-only
// bf16 pack; permuted-V; static-max softmax (wq pre-scaled); ones-MFMA denominator
// (lf[r] = l for q=fg*4+r, lane-local epilogue); 48KB LDS -> 3 blocks/CU.
__global__ __launch_bounds__(256, 3) void k_flash_attn14(
    const unsigned short* __restrict__ qkv, const unsigned short* __restrict__ vT,
    unsigned short* __restrict__ attn) {
  int g0 = (int)blockIdx.x;
  int hb = g0 & 63;
  int h = hb & 31, b = hb >> 5;
  int qt = 15 - (g0 >> 6);            // heavy blocks first (backfill smooths the tail)
  int g = h >> 2;
  int t = threadIdx.x, lane = t & 63, wave = t >> 6;
  int fr = lane & 15, fg = lane >> 4;

  __shared__ __align__(16) char KT[16384];              // 16KB: K tile [128 rows][128B], swz
  __shared__ __align__(16) char VT2[2][16384];          // 32KB: V tile [64 rows][256B], swz, dbuf
  long rowbase = (long)b * LSEQ;

  int qbaseA = qt * 128 + wave * 32;
  int qbaseB = qbaseA + 16;

  const unsigned short* qpA = &qkv[(rowbase + qbaseA + fr) * NQKV + h * 64 + fg * 8];
  const unsigned short* qpB = &qkv[(rowbase + qbaseB + fr) * NQKV + h * 64 + fg * 8];
  bf16x8 qfA0 = *(const bf16x8*)(qpA);
  bf16x8 qfA1 = *(const bf16x8*)(qpA + 32);
  bf16x8 qfB0 = *(const bf16x8*)(qpB);
  bf16x8 qfB1 = *(const bf16x8*)(qpB + 32);

  int kcb = ((t & 7) * 16) ^ (((t >> 3) & 7) << 4);    // K: 128B rows, row = p*32 + (t>>3)
  int vcb = ((t & 15) * 16) ^ (((t >> 4) & 7) << 4);   // V: 256B rows, row = p*16 + (t>>4)

  const char* kgb = (const char*)qkv;
  const char* vgb = (const char*)vT;
  long ksrc0 = ((rowbase) * (long)NQKV + KOFF + (long)g * 64) * 2;
  long vsrc0 = (((long)(b * 512 + g * 64)) * LSEQ) * 2;

  auto stageK = [&](int kbase) {
    #pragma unroll
    for (int p = 0; p < 4; p++) {
      int krow = p * 32 + (t >> 3);
      gload_lds16(kgb + ksrc0 + (long)(kbase + krow) * (NQKV * 2) + kcb,
                  KT + p * 4096 + t * 16);
    }
  };
  auto stageV = [&](int kbase, char* dst) {
    #pragma unroll
    for (int p = 0; p < 4; p++) {
      int vrow = p * 16 + (t >> 4);
      gload_lds16(vgb + vsrc0 + (long)vrow * (LSEQ * 2) + kbase * 2 + vcb,
                  dst + p * 4096 + t * 16);
    }
  };

  stageK(0);
  stageV(0, VT2[0]);

  f32x4 poA[4] = {}, poB[4] = {};
  f32x4 lfA = {}, lfB = {};           // MFMA-accumulated row-sums of P (denominator)
  bf16x8 onesv;
  #pragma unroll
  for (int i = 0; i < 8; i++) onesv[i] = (__bf16)1.0f;

  int sw8 = (fr & 7) << 4;

  for (int kt = 0; kt <= qt; kt++) {
    int kbase = kt * 128;
    __syncthreads();   // B1: staged K/V landed; all waves' prev-iter LDS reads done

    // V restage WAR-safe at B1 (prev PV readers of this buffer synced); full-iter cover
    if (kt < qt) stageV(kbase + 128, VT2[(kt + 1) & 1]);

    f32x4 stA[8], stB[8];
    __builtin_amdgcn_s_setprio(1);
    #pragma unroll
    for (int s = 0; s < 8; s++) {
      const char* kr = KT + ((s * 16 + fr) << 7);
      bf16x8 kf0 = *(const bf16x8*)(kr + ((fg * 16) ^ sw8));
      bf16x8 kf1 = *(const bf16x8*)(kr + ((fg * 16 + 64) ^ sw8));
      f32x4 a = {};
      a = __builtin_amdgcn_mfma_f32_16x16x32_bf16(kf0, qfA0, a, 0, 0, 0);
      a = __builtin_amdgcn_mfma_f32_16x16x32_bf16(kf1, qfA1, a, 0, 0, 0);
      stA[s] = a;
      f32x4 c = {};
      c = __builtin_amdgcn_mfma_f32_16x16x32_bf16(kf0, qfB0, c, 0, 0, 0);
      c = __builtin_amdgcn_mfma_f32_16x16x32_bf16(kf1, qfB1, c, 0, 0, 0);
      stB[s] = c;
    }
    __builtin_amdgcn_s_setprio(0);
    __syncthreads();   // B2: all waves' K ds_reads retired -> K restage safe

    if (kt < qt) stageK(kbase + 128);   // lands by next B1; softmax+PV cover

    if (kt == qt) {   // diagonal tile: causal mask (k = kbase+s*16+fg*4+r, q = qbase+fr)
      #pragma unroll
      for (int s = 0; s < 8; s++) {
        #pragma unroll
        for (int r = 0; r < 4; r++) {
          int kp = kbase + s * 16 + fg * 4 + r;
          if (kp > qbaseA + fr) stA[s][r] = -1e30f;
          if (kp > qbaseB + fr) stB[s][r] = -1e30f;
        }
      }
    }

    // softmax (static-max, pre-scaled exp2 domain) + register-only bf16 pack.
    // A-frag slot (fg, j): j=r -> k32 = 4*fg + r ; j=4+r -> k32 = 16 + 4*fg + r.
    bf16x8 paA[4], paB[4];
    #pragma unroll
    for (int km = 0; km < 4; km++) {
      bf16x8 pa, pb;
      #pragma unroll
      for (int r = 0; r < 4; r++) {
        pa[r]     = (__bf16)exp2f(stA[2 * km][r]);
        pa[r + 4] = (__bf16)exp2f(stA[2 * km + 1][r]);
        pb[r]     = (__bf16)exp2f(stB[2 * km][r]);
        pb[r + 4] = (__bf16)exp2f(stB[2 * km + 1][r]);
      }
      paA[km] = pa;
      paB[km] = pb;
    }

    const char* Vb = VT2[kt & 1];
    __builtin_amdgcn_s_setprio(1);
    #pragma unroll
    for (int km = 0; km < 4; km++) {
      lfA = __builtin_amdgcn_mfma_f32_16x16x32_bf16(paA[km], onesv, lfA, 0, 0, 0);
      lfB = __builtin_amdgcn_mfma_f32_16x16x32_bf16(paB[km], onesv, lfB, 0, 0, 0);
      #pragma unroll
      for (int dt = 0; dt < 4; dt++) {
        const char* vr = Vb + ((dt * 16 + fr) << 8);
        bf16x8 vf = *(const bf16x8*)(vr + ((km * 64 + fg * 16) ^ sw8));
        poA[dt] = __builtin_amdgcn_mfma_f32_16x16x32_bf16(paA[km], vf, poA[dt], 0, 0, 0);
        poB[dt] = __builtin_amdgcn_mfma_f32_16x16x32_bf16(paB[km], vf, poB[dt], 0, 0, 0);
      }
    }
    __builtin_amdgcn_s_setprio(0);
    // no trailing barrier: next B1 orders LDS reads vs. restaging
  }

  // denominator is lane-local: lf[r] = l for q = fg*4+r (identical on every lane's col)
  #pragma unroll
  for (int r = 0; r < 4; r++) {
    float liA = 1.0f / lfA[r];
    float liB = 1.0f / lfB[r];
    #pragma unroll
    for (int dt = 0; dt < 4; dt++) {
      attn[(rowbase + qbaseA + fg * 4 + r) * DIM + h * 64 + dt * 16 + fr] = f2bf(poA[dt][r] * liA);
      attn[(rowbase + qbaseB + fg * 4 + r) * DIM + h * 64 + dt * 16 + fr] = f2bf(poB[dt][r] * liB);
    }
  }
}

extern "C" void kernel_launch(void* const* d_in, const int* in_sizes, int n_in,
                              void* d_out, int out_size, void* d_ws, size_t ws_size,
                              hipStream_t stream) {
  const float* x  = (const float*)d_in[0];
  const float* wq = (const float*)d_in[1];
  const float* wk = (const float*)d_in[2];
  const float* wv = (const float*)d_in[3];
  const float* wo = (const float*)d_in[4];

  char* ws = (char*)d_ws;
  unsigned short* xb    = (unsigned short*)(ws);                 // 16.78 MB (reused as vT later)
  unsigned short* wqkvT = (unsigned short*)(ws + 16777216);      // 12.58 MB [3072][2048]
  unsigned short* woT   = (unsigned short*)(ws + 29360128);      //  8.39 MB [2048][2048]
  unsigned short* qkv   = (unsigned short*)(ws + 37748736);      // 25.17 MB [4096][3072]
  unsigned short* attn  = (unsigned short*)(ws + 62914560);      // 16.78 MB [4096][2048]
  float* cosT           = (float*)(ws + 79691776);               // 256 KB
  float* sinT           = (float*)(ws + 79953920);               // 256 KB
  unsigned short* vT    = xb;                                    // alias: xb dead after QKV GEMM

  const float C2 = 0.125f * 1.44269504f;   // 1/sqrt(64) * log2(e), folded into wq

  k_cvt_x<<<8192, 256, 0, stream>>>(x, xb, M_ROWS * DIM / 4);
  dim3 tb(32, 8);
  // fused weight transposes: one launch, 4 z-sections
  k_transpose_all<<<dim3(64, 64, 4), tb, 0, stream>>>(wq, wk, wv, wo, wqkvT, woT, C2);
  k_rope_table<<<(LSEQ*32)/256, 256, 0, stream>>>(cosT, sinT);

  // QKV: 128^2 BK=64, 512 threads / 8 waves (r13-verified) + fused RoPE + XCD swizzle
  k_gemm_bt<true, true><<<(M_ROWS/128)*(NQKV/128), 512, 0, stream>>>(
      xb, wqkvT, qkv, M_ROWS, NQKV, DIM, NQKV/128, cosT, sinT);
  k_transpose_v<<<dim3(16, 64, 2), tb, 0, stream>>>(qkv, vT);
  // flash: r14-verified 4-wave kernel (64.5us)
  k_flash_attn14<<<1024, 256, 0, stream>>>(qkv, vT, attn);
  // WO: r13-verified 128^2 dbuf single-barrier pipeline + XCD swizzle
  k_gemm_db<<<(M_ROWS/128)*(DIM/128), 512, 0, stream>>>(
      attn, woT, (float*)d_out, M_ROWS, DIM, DIM, DIM/128);
}

// Round 18
// 172.708 us; speedup vs baseline: 1.7423x; 1.0343x over previous
//
#include <hip/hip_runtime.h>
#include <stdint.h>

#define DIM   2048
#define LSEQ  2048
#define BATCH 2
#define NH    32
#define NKV   8
#define HD    64
#define M_ROWS (BATCH*LSEQ)       // 4096
#define NQKV  (DIM + 2*NKV*HD)    // 3072
#define KOFF  DIM                 // 2048
#define VOFF  (DIM + NKV*HD)      // 2560

typedef __attribute__((ext_vector_type(8))) __bf16 bf16x8;
typedef __attribute__((ext_vector_type(8))) unsigned short u16x8;
typedef __attribute__((ext_vector_type(4))) float f32x4;

// hardware RNE f32->bf16 (harness-verified rounds 2-17)
__device__ __forceinline__ unsigned short f2bf(float f) {
  union { __bf16 h; unsigned short u; } v;
  v.h = (__bf16)f;
  return v.u;
}
__device__ __forceinline__ float bf2f(unsigned short h) {
  union { unsigned u; float f; } v; v.u = ((unsigned)h) << 16;
  return v.f;
}

__device__ __forceinline__ void gload_lds16(const void* g, void* l) {
  __builtin_amdgcn_global_load_lds(
      (__attribute__((address_space(1))) unsigned int*)g,
      (__attribute__((address_space(3))) unsigned int*)l, 16, 0, 0);
}

// ---------------- fp32 -> bf16 convert (vectorized) ----------------
__global__ void k_cvt_x(const float* __restrict__ in, unsigned short* __restrict__ out, int n4) {
  int i = blockIdx.x * blockDim.x + threadIdx.x;
  if (i >= n4) return;
  float4 v = ((const float4*)in)[i];
  ushort4 o;
  o.x = f2bf(v.x); o.y = f2bf(v.y); o.z = f2bf(v.z); o.w = f2bf(v.w);
  ((ushort4*)out)[i] = o;
}

// ---------------- fused weight transposes + RoPE tables: 5 launches -> 1 ----------------
// sec 0-3: weight transposes (wq carries the C2 = 0.125*log2(e) softmax fold).
// sec 4: RoPE cos/sin tables (first 256 blocks; 256 elements each; same thread shape).
__global__ void k_transpose_all(const float* __restrict__ wq, const float* __restrict__ wk,
                                const float* __restrict__ wv, const float* __restrict__ wo,
                                unsigned short* __restrict__ wqkvT,
                                unsigned short* __restrict__ woT,
                                float* __restrict__ cosT, float* __restrict__ sinT,
                                float C2) {
  int sec = blockIdx.z;
  if (sec == 4) {   // RoPE tables: idx < 256 blocks x 256 threads = LSEQ*32 elements
    int idx = blockIdx.y * 64 + blockIdx.x;
    if (idx >= 256) return;
    int i = idx * 256 + threadIdx.y * 32 + threadIdx.x;
    int tpos = i >> 5, j = i & 31;
    float inv = powf(10000.0f, -(float)j / 32.0f);
    float fr = (float)tpos * inv;
    cosT[i] = cosf(fr);
    sinT[i] = sinf(fr);
    return;
  }
  __shared__ float tile[32][33];
  const float* in; unsigned short* out; int N; float scale = 1.0f;
  if (sec == 0)      { in = wq; out = wqkvT;                     N = DIM; scale = C2; }
  else if (sec == 1) { in = wk; out = wqkvT + (long)2048 * 2048; N = 512; }
  else if (sec == 2) { in = wv; out = wqkvT + (long)2560 * 2048; N = 512; }
  else               { in = wo; out = woT;                       N = DIM; }
  int n0 = blockIdx.x * 32;
  if (n0 >= N) return;
  int k0 = blockIdx.y * 32;
  int tx = threadIdx.x, ty = threadIdx.y;
  #pragma unroll
  for (int i = ty; i < 32; i += 8)
    tile[i][tx] = in[(long)(k0 + i) * N + n0 + tx];
  __syncthreads();
  #pragma unroll
  for (int i = ty; i < 32; i += 8)
    out[(long)(n0 + i) * DIM + k0 + tx] = f2bf(scale * tile[tx][i]);
}

// ---------------- transpose V section of qkv -> vT, k-PERMUTED columns ----------------
// Column position e holds original k = tx with e = 8*((tx>>2)&3) + 4*(tx>>4) + (tx&3),
// matching flash's in-register-P A-fragment k-order (round 6/7, verified).
__global__ void k_transpose_v(const unsigned short* __restrict__ qkv,
                              unsigned short* __restrict__ vT) {
  __shared__ unsigned short tile[32][33];
  int c0 = blockIdx.x * 32;   // within 512 (= g*64+d)
  int l0 = blockIdx.y * 32;
  int b  = blockIdx.z;
  int tx = threadIdx.x, ty = threadIdx.y;
  #pragma unroll
  for (int i = ty; i < 32; i += 8)
    tile[i][tx] = qkv[((long)b * LSEQ + l0 + i) * NQKV + VOFF + c0 + tx];
  __syncthreads();
  int e = 8 * ((tx >> 2) & 3) + 4 * (tx >> 4) + (tx & 3);
  #pragma unroll
  for (int i = ty; i < 32; i += 8)
    vT[((long)b * 512 + c0 + i) * LSEQ + l0 + e] = tile[tx][i];
}

// ---------------- GEMM v8 (QKV): 128^2 tile, BK=64, 512 thr / 8 waves (r13-verified) ----------------
// No XCD swizzle: r17 A/B showed it costs ~2% here (operands are L3-fit; catalog m160).
template<bool BF16OUT, bool ROPE>
__global__ __launch_bounds__(512, 4) void k_gemm_bt(
    const unsigned short* __restrict__ A, const unsigned short* __restrict__ Bt,
    void* __restrict__ Cv, int M, int N, int K,
    const float* __restrict__ cosT, const float* __restrict__ sinT) {
  __shared__ __align__(16) char AsB[16384];   // [128 rows][128B], swizzled
  __shared__ __align__(16) char BsB[16384];
  int t = threadIdx.x;
  int lane = t & 63, wave = t >> 6;        // 0..7
  int fr = lane & 15, fg = lane >> 4;
  int wm = wave >> 1, wn = wave & 1;       // 4M x 2N quadrants: 32 rows x 64 cols
  long rowA = (long)blockIdx.x * 128;
  long rowB = (long)blockIdx.y * 128;
  long K2 = (long)K * 2;

  int scol = ((t & 7) * 16) ^ (((t >> 3) & 7) << 4);
  const char* ApB = (const char*)A  + (rowA + (t >> 3)) * K2 + scol;
  const char* BpB = (const char*)Bt + (rowB + (t >> 3)) * K2 + scol;

  f32x4 acc[2][4] = {};
  int sw8 = (fr & 7) << 4;

  for (int kt = 0; kt < K; kt += 64) {
    #pragma unroll
    for (int p = 0; p < 2; p++) {
      gload_lds16(ApB + (long)(p * 64) * K2 + kt * 2, AsB + p * 8192 + t * 16);
      gload_lds16(BpB + (long)(p * 64) * K2 + kt * 2, BsB + p * 8192 + t * 16);
    }
    __syncthreads();
    #pragma unroll
    for (int ks = 0; ks < 2; ks++) {
      bf16x8 af[2], bfv[4];
      #pragma unroll
      for (int i = 0; i < 2; i++)
        af[i] = *(const bf16x8*)(AsB + (wm * 32 + i * 16 + fr) * 128 + ((ks * 64 + fg * 16) ^ sw8));
      #pragma unroll
      for (int j = 0; j < 4; j++)
        bfv[j] = *(const bf16x8*)(BsB + (wn * 64 + j * 16 + fr) * 128 + ((ks * 64 + fg * 16) ^ sw8));
      #pragma unroll
      for (int i = 0; i < 2; i++) {
        #pragma unroll
        for (int j = 0; j < 4; j++)
          acc[i][j] = __builtin_amdgcn_mfma_f32_16x16x32_bf16(af[i], bfv[j], acc[i][j], 0, 0, 0);
      }
    }
    __syncthreads();
  }

  long colbase = rowB + wn * 64;
  bool rope_sec = ROPE && (colbase < VOFF);   // Q or K head (col < 2560); wave-uniform
  #pragma unroll
  for (int i = 0; i < 2; i++) {
    #pragma unroll
    for (int r = 0; r < 4; r++) {
      long row = rowA + wm * 32 + i * 16 + fg * 4 + r;
      if (ROPE && rope_sec) {
        int tpos = (int)(row & (LSEQ - 1));
        #pragma unroll
        for (int j = 0; j < 2; j++) {   // pair (d = j*16+fr, d+32 = (j+2)*16+fr)
          int jj = j * 16 + fr;
          float c = cosT[tpos * 32 + jj];
          float s = sinT[tpos * 32 + jj];
          float lo = acc[i][j][r], hi = acc[i][j + 2][r];
          ((unsigned short*)Cv)[row * N + colbase + j * 16 + fr]       = f2bf(lo * c - hi * s);
          ((unsigned short*)Cv)[row * N + colbase + (j + 2) * 16 + fr] = f2bf(hi * c + lo * s);
        }
      } else {
        #pragma unroll
        for (int j = 0; j < 4; j++) {
          long col = colbase + j * 16 + fr;
          if (BF16OUT) ((unsigned short*)Cv)[row * N + col] = f2bf(acc[i][j][r]);
          else         ((float*)Cv)[row * N + col] = acc[i][j][r];
        }
      }
    }
  }
}

// ---------------- GEMM v9 (WO): 128^2 dbuf single-barrier pipeline, 512 threads (r13-verified) ----------------
__global__ __launch_bounds__(512, 4) void k_gemm_db(
    const unsigned short* __restrict__ A, const unsigned short* __restrict__ Bt,
    float* __restrict__ Cv, int M, int N, int K) {
  __shared__ __align__(16) char AsB[2][16384];   // [buf][128 rows][128B], swizzled
  __shared__ __align__(16) char BsB[2][16384];
  int t = threadIdx.x;
  int lane = t & 63, wave = t >> 6;
  int fr = lane & 15, fg = lane >> 4;
  int wm = wave >> 1, wn = wave & 1;       // 4M x 2N quadrants: 32 rows x 64 cols
  long rowA = (long)blockIdx.x * 128;
  long rowB = (long)blockIdx.y * 128;
  long K2 = (long)K * 2;

  int scol = ((t & 7) * 16) ^ (((t >> 3) & 7) << 4);
  const char* ApB = (const char*)A  + (rowA + (t >> 3)) * K2 + scol;
  const char* BpB = (const char*)Bt + (rowB + (t >> 3)) * K2 + scol;

  auto stage = [&](int kt, int bi) {   // kt in 64-elem tiles; 4 loads/thread
    #pragma unroll
    for (int p = 0; p < 2; p++) {
      gload_lds16(ApB + (long)(p * 64) * K2 + (long)kt * 128, AsB[bi] + p * 8192 + t * 16);
      gload_lds16(BpB + (long)(p * 64) * K2 + (long)kt * 128, BsB[bi] + p * 8192 + t * 16);
    }
  };

  f32x4 acc[2][4] = {};
  int sw8 = (fr & 7) << 4;
  int NT = K >> 6;

  stage(0, 0);
  for (int kt = 0; kt < NT; kt++) {
    int cur = kt & 1;
    // tile kt's 4 loads are the only outstanding VMEM; issued a full iteration ago
    asm volatile("s_waitcnt vmcnt(0)" ::: "memory");
    __builtin_amdgcn_s_barrier();
    __builtin_amdgcn_sched_barrier(0);
    const char* Ac = AsB[cur];
    const char* Bc = BsB[cur];
    #pragma unroll
    for (int ks = 0; ks < 2; ks++) {
      bf16x8 af[2], bfv[4];
      #pragma unroll
      for (int i = 0; i < 2; i++)
        af[i] = *(const bf16x8*)(Ac + (wm * 32 + i * 16 + fr) * 128 + ((ks * 64 + fg * 16) ^ sw8));
      #pragma unroll
      for (int j = 0; j < 4; j++)
        bfv[j] = *(const bf16x8*)(Bc + (wn * 64 + j * 16 + fr) * 128 + ((ks * 64 + fg * 16) ^ sw8));
      if (ks == 0 && kt + 1 < NT) stage(kt + 1, cur ^ 1);   // issue under reads+MFMA
      #pragma unroll
      for (int i = 0; i < 2; i++) {
        #pragma unroll
        for (int j = 0; j < 4; j++)
          acc[i][j] = __builtin_amdgcn_mfma_f32_16x16x32_bf16(af[i], bfv[j], acc[i][j], 0, 0, 0);
      }
    }
  }

  #pragma unroll
  for (int i = 0; i < 2; i++) {
    #pragma unroll
    for (int j = 0; j < 4; j++) {
      #pragma unroll
      for (int r = 0; r < 4; r++) {
        long row = rowA + wm * 32 + i * 16 + fg * 4 + r;
        long col = rowB + wn * 64 + j * 16 + fr;
        Cv[row * N + col] = acc[i][j][r];
      }
    }
  }
}

// ---------------- flash attention v17 (r14-verified, 64.5us) ----------------
// 4-wave, 128 q-rows/block. Swapped QK (mfma(K,Q)) -> P lane-local; register-only bf16
// pack (rule #20); permuted-V; static-max softmax (wq pre-scaled into exp2 domain);
// ones-MFMA denominator (lane-local epilogue); 48KB LDS -> 3 blocks/CU. 8-wave variants
// (r15/r16) spill: wave-dependent causal mask defeats the last-iteration peel that
// keeps stA/stB in registers. Loop-uniform mask (kt==qt) is load-bearing.
__global__ __launch_bounds__(256, 3) void k_flash_attn14(
    const unsigned short* __restrict__ qkv, const unsigned short* __restrict__ vT,
    unsigned short* __restrict__ attn) {
  int g0 = (int)blockIdx.x;
  int hb = g0 & 63;
  int h = hb & 31, b = hb >> 5;
  int qt = 15 - (g0 >> 6);            // heavy blocks first (backfill smooths the tail)
  int g = h >> 2;
  int t = threadIdx.x, lane = t & 63, wave = t >> 6;
  int fr = lane & 15, fg = lane >> 4;

  __shared__ __align__(16) char KT[16384];              // 16KB: K tile [128 rows][128B], swz
  __shared__ __align__(16) char VT2[2][16384];          // 32KB: V tile [64 rows][256B], swz, dbuf
  long rowbase = (long)b * LSEQ;

  int qbaseA = qt * 128 + wave * 32;
  int qbaseB = qbaseA + 16;

  const unsigned short* qpA = &qkv[(rowbase + qbaseA + fr) * NQKV + h * 64 + fg * 8];
  const unsigned short* qpB = &qkv[(rowbase + qbaseB + fr) * NQKV + h * 64 + fg * 8];
  bf16x8 qfA0 = *(const bf16x8*)(qpA);
  bf16x8 qfA1 = *(const bf16x8*)(qpA + 32);
  bf16x8 qfB0 = *(const bf16x8*)(qpB);
  bf16x8 qfB1 = *(const bf16x8*)(qpB + 32);

  int kcb = ((t & 7) * 16) ^ (((t >> 3) & 7) << 4);    // K: 128B rows, row = p*32 + (t>>3)
  int vcb = ((t & 15) * 16) ^ (((t >> 4) & 7) << 4);   // V: 256B rows, row = p*16 + (t>>4)

  const char* kgb = (const char*)qkv;
  const char* vgb = (const char*)vT;
  long ksrc0 = ((rowbase) * (long)NQKV + KOFF + (long)g * 64) * 2;
  long vsrc0 = (((long)(b * 512 + g * 64)) * LSEQ) * 2;

  auto stageK = [&](int kbase) {
    #pragma unroll
    for (int p = 0; p < 4; p++) {
      int krow = p * 32 + (t >> 3);
      gload_lds16(kgb + ksrc0 + (long)(kbase + krow) * (NQKV * 2) + kcb,
                  KT + p * 4096 + t * 16);
    }
  };
  auto stageV = [&](int kbase, char* dst) {
    #pragma unroll
    for (int p = 0; p < 4; p++) {
      int vrow = p * 16 + (t >> 4);
      gload_lds16(vgb + vsrc0 + (long)vrow * (LSEQ * 2) + kbase * 2 + vcb,
                  dst + p * 4096 + t * 16);
    }
  };

  stageK(0);
  stageV(0, VT2[0]);

  f32x4 poA[4] = {}, poB[4] = {};
  f32x4 lfA = {}, lfB = {};           // MFMA-accumulated row-sums of P (denominator)
  bf16x8 onesv;
  #pragma unroll
  for (int i = 0; i < 8; i++) onesv[i] = (__bf16)1.0f;

  int sw8 = (fr & 7) << 4;

  for (int kt = 0; kt <= qt; kt++) {
    int kbase = kt * 128;
    __syncthreads();   // B1: staged K/V landed; all waves' prev-iter LDS reads done

    // V restage WAR-safe at B1 (prev PV readers of this buffer synced); full-iter cover
    if (kt < qt) stageV(kbase + 128, VT2[(kt + 1) & 1]);

    f32x4 stA[8], stB[8];
    __builtin_amdgcn_s_setprio(1);
    #pragma unroll
    for (int s = 0; s < 8; s++) {
      const char* kr = KT + ((s * 16 + fr) << 7);
      bf16x8 kf0 = *(const bf16x8*)(kr + ((fg * 16) ^ sw8));
      bf16x8 kf1 = *(const bf16x8*)(kr + ((fg * 16 + 64) ^ sw8));
      f32x4 a = {};
      a = __builtin_amdgcn_mfma_f32_16x16x32_bf16(kf0, qfA0, a, 0, 0, 0);
      a = __builtin_amdgcn_mfma_f32_16x16x32_bf16(kf1, qfA1, a, 0, 0, 0);
      stA[s] = a;
      f32x4 c = {};
      c = __builtin_amdgcn_mfma_f32_16x16x32_bf16(kf0, qfB0, c, 0, 0, 0);
      c = __builtin_amdgcn_mfma_f32_16x16x32_bf16(kf1, qfB1, c, 0, 0, 0);
      stB[s] = c;
    }
    __builtin_amdgcn_s_setprio(0);
    __syncthreads();   // B2: all waves' K ds_reads retired -> K restage safe

    if (kt < qt) stageK(kbase + 128);   // lands by next B1; softmax+PV cover

    if (kt == qt) {   // diagonal tile: causal mask (k = kbase+s*16+fg*4+r, q = qbase+fr)
      #pragma unroll
      for (int s = 0; s < 8; s++) {
        #pragma unroll
        for (int r = 0; r < 4; r++) {
          int kp = kbase + s * 16 + fg * 4 + r;
          if (kp > qbaseA + fr) stA[s][r] = -1e30f;
          if (kp > qbaseB + fr) stB[s][r] = -1e30f;
        }
      }
    }

    // softmax (static-max, pre-scaled exp2 domain) + register-only bf16 pack.
    // A-frag slot (fg, j): j=r -> k32 = 4*fg + r ; j=4+r -> k32 = 16 + 4*fg + r.
    bf16x8 paA[4], paB[4];
    #pragma unroll
    for (int km = 0; km < 4; km++) {
      bf16x8 pa, pb;
      #pragma unroll
      for (int r = 0; r < 4; r++) {
        pa[r]     = (__bf16)exp2f(stA[2 * km][r]);
        pa[r + 4] = (__bf16)exp2f(stA[2 * km + 1][r]);
        pb[r]     = (__bf16)exp2f(stB[2 * km][r]);
        pb[r + 4] = (__bf16)exp2f(stB[2 * km + 1][r]);
      }
      paA[km] = pa;
      paB[km] = pb;
    }

    const char* Vb = VT2[kt & 1];
    __builtin_amdgcn_s_setprio(1);
    #pragma unroll
    for (int km = 0; km < 4; km++) {
      lfA = __builtin_amdgcn_mfma_f32_16x16x32_bf16(paA[km], onesv, lfA, 0, 0, 0);
      lfB = __builtin_amdgcn_mfma_f32_16x16x32_bf16(paB[km], onesv, lfB, 0, 0, 0);
      #pragma unroll
      for (int dt = 0; dt < 4; dt++) {
        const char* vr = Vb + ((dt * 16 + fr) << 8);
        bf16x8 vf = *(const bf16x8*)(vr + ((km * 64 + fg * 16) ^ sw8));
        poA[dt] = __builtin_amdgcn_mfma_f32_16x16x32_bf16(paA[km], vf, poA[dt], 0, 0, 0);
        poB[dt] = __builtin_amdgcn_mfma_f32_16x16x32_bf16(paB[km], vf, poB[dt], 0, 0, 0);
      }
    }
    __builtin_amdgcn_s_setprio(0);
    // no trailing barrier: next B1 orders LDS reads vs. restaging
  }

  // denominator is lane-local: lf[r] = l for q = fg*4+r (identical on every lane's col)
  #pragma unroll
  for (int r = 0; r < 4; r++) {
    float liA = 1.0f / lfA[r];
    float liB = 1.0f / lfB[r];
    #pragma unroll
    for (int dt = 0; dt < 4; dt++) {
      attn[(rowbase + qbaseA + fg * 4 + r) * DIM + h * 64 + dt * 16 + fr] = f2bf(poA[dt][r] * liA);
      attn[(rowbase + qbaseB + fg * 4 + r) * DIM + h * 64 + dt * 16 + fr] = f2bf(poB[dt][r] * liB);
    }
  }
}

extern "C" void kernel_launch(void* const* d_in, const int* in_sizes, int n_in,
                              void* d_out, int out_size, void* d_ws, size_t ws_size,
                              hipStream_t stream) {
  const float* x  = (const float*)d_in[0];
  const float* wq = (const float*)d_in[1];
  const float* wk = (const float*)d_in[2];
  const float* wv = (const float*)d_in[3];
  const float* wo = (const float*)d_in[4];

  char* ws = (char*)d_ws;
  unsigned short* xb    = (unsigned short*)(ws);                 // 16.78 MB (reused as vT later)
  unsigned short* wqkvT = (unsigned short*)(ws + 16777216);      // 12.58 MB [3072][2048]
  unsigned short* woT   = (unsigned short*)(ws + 29360128);      //  8.39 MB [2048][2048]
  unsigned short* qkv   = (unsigned short*)(ws + 37748736);      // 25.17 MB [4096][3072]
  unsigned short* attn  = (unsigned short*)(ws + 62914560);      // 16.78 MB [4096][2048]
  float* cosT           = (float*)(ws + 79691776);               // 256 KB
  float* sinT           = (float*)(ws + 79953920);               // 256 KB
  unsigned short* vT    = xb;                                    // alias: xb dead after QKV GEMM

  const float C2 = 0.125f * 1.44269504f;   // 1/sqrt(64) * log2(e), folded into wq

  k_cvt_x<<<8192, 256, 0, stream>>>(x, xb, M_ROWS * DIM / 4);
  dim3 tb(32, 8);
  // fused weight transposes + RoPE tables: one launch, 5 z-sections
  k_transpose_all<<<dim3(64, 64, 5), tb, 0, stream>>>(wq, wk, wv, wo, wqkvT, woT, cosT, sinT, C2);

  // QKV: 128^2 BK=64, 512 threads / 8 waves (r13-verified) + fused RoPE epilogue
  k_gemm_bt<true, true><<<dim3(M_ROWS/128, NQKV/128), 512, 0, stream>>>(
      xb, wqkvT, qkv, M_ROWS, NQKV, DIM, cosT, sinT);
  k_transpose_v<<<dim3(16, 64, 2), tb, 0, stream>>>(qkv, vT);
  // flash: r14-verified 4-wave kernel (64.5us)
  k_flash_attn14<<<1024, 256, 0, stream>>>(qkv, vT, attn);
  // WO: r13-verified 128^2 dbuf single-barrier pipeline, 512 threads
  k_gemm_db<<<dim3(M_ROWS/128, DIM/128), 512, 0, stream>>>(
      attn, woT, (float*)d_out, M_ROWS, DIM, DIM);
}